// Round 16
// baseline (66.810 us; speedup 1.0000x reference)
//
#include <hip/hip_runtime.h>
#include <hip/hip_bf16.h>
#include <math.h>

#define NB 32      // B
#define NV 1024    // V
#define NFT 16     // F
#define NA 32      // A
#define NP 64      // P
#define NOUT 128   // NF
#define NC 96      // C = P + A
#define NC2 192    // 2C

#define NSPLIT 16            // V splits
#define VPB 64               // rows per block

typedef __attribute__((ext_vector_type(8))) short bf16x8;
typedef __attribute__((ext_vector_type(4))) float f32x4;

// ---------------------------------------------------------------------------
// K2p: R9 body, x1 (measured 10.1 us in R15 diagnostic).
// ---------------------------------------------------------------------------
__global__ __launch_bounds__(512, 2)
void k2p(const float* __restrict__ x,
         const float* __restrict__ W_flr,
         const float* __restrict__ b_flr,
         const float* __restrict__ W_s,
         const float* __restrict__ b_s,
         float* __restrict__ ewbuf,
         float* __restrict__ part) {
    __shared__ float xs[VPB][NFT];        // 4 KB
    __shared__ float fs[VPB][NC];         // 24 KB

    int b = blockIdx.x, vs = blockIdx.y, tid = threadIdx.x;
    int rowbase = b * NV + vs * VPB;

    if (tid < 256) {
        const float4* xsrc = (const float4*)(x + (size_t)rowbase * NFT);
        ((float4*)xs)[tid] = xsrc[tid];
    }
    __syncthreads();

    // phase A: c = tid&127 (<96 active), rh = tid>>7 -> rows rh*16..+15
    {
        int c  = tid & 127;
        int rh = tid >> 7;
        if (c < NC) {
            float Wcol[NFT], bias;
            if (c < NP) {
                bias = b_flr[c];
#pragma unroll
                for (int k = 0; k < NFT; ++k) Wcol[k] = W_flr[k * NP + c];
            } else {
                int a = c - NP;
                bias = b_s[a];
#pragma unroll
                for (int k = 0; k < NFT; ++k) Wcol[k] = W_s[k * NA + a];
            }
#pragma unroll
            for (int r0 = 0; r0 < 16; ++r0) {
                int r = rh * 16 + r0;
                float xr[NFT];
#pragma unroll
                for (int q = 0; q < 4; ++q)
                    ((float4*)xr)[q] = ((const float4*)xs[r])[q];
                float acc = bias;
#pragma unroll
                for (int k = 0; k < NFT; ++k)
                    acc = fmaf(xr[k], Wcol[k], acc);
                if (c >= NP) {
                    acc = __expf(-acc * acc);
                    ewbuf[(size_t)(rowbase + r) * NA + (c - NP)] = acc;
                }
                fs[r][c] = acc;
            }
        }
    }
    __syncthreads();

    // phase B: thread owns 1a x 6c over all 64 rows
    int a  = tid >> 4;
    int c0 = (tid & 15) * 6;
    int ea = NP + a;

    float sm[6], mx[6];
#pragma unroll
    for (int j = 0; j < 6; ++j) { sm[j] = 0.f; mx[j] = -INFINITY; }

#pragma unroll 4
    for (int r = 0; r < VPB; ++r) {
        float e = fs[r][ea];
        float2 fA = *(const float2*)&fs[r][c0];
        float2 fB = *(const float2*)&fs[r][c0 + 2];
        float2 fC = *(const float2*)&fs[r][c0 + 4];
        float ff[6] = {fA.x, fA.y, fB.x, fB.y, fC.x, fC.y};
#pragma unroll
        for (int j = 0; j < 6; ++j) {
            float p = e * ff[j];
            sm[j] += p;
            mx[j] = fmaxf(mx[j], p);
        }
    }

    float* pb = part + (size_t)((b * NSPLIT + vs) * NA + a) * NC2;
#pragma unroll
    for (int q = 0; q < 3; ++q) {
        float2 vm = {mx[2 * q], mx[2 * q + 1]};
        float2 vsum = {sm[2 * q], sm[2 * q + 1]};
        *(float2*)&pb[c0 + 2 * q]      = vm;
        *(float2*)&pb[NC + c0 + 2 * q] = vsum;
    }
}

// ---------------------------------------------------------------------------
// K23: DIAGNOSTIC x3 repeat (idempotent reps, barrier-separated).
// ---------------------------------------------------------------------------
__global__ void k23(const float* __restrict__ part,
                    const float* __restrict__ W_out,
                    float* __restrict__ Gp) {
    __shared__ float aggL[NC2];
    int b = blockIdx.x, a = blockIdx.y, tid = threadIdx.x;

#pragma unroll 1
    for (int rep = 0; rep < 3; ++rep) {
        {
            const float* pb = part + (size_t)(b * NSPLIT * NA + a) * NC2 + tid;
            const size_t stride = (size_t)NA * NC2;
            if (tid < NC) {
                float m = -INFINITY;
#pragma unroll
                for (int vsi = 0; vsi < NSPLIT; ++vsi)
                    m = fmaxf(m, pb[vsi * stride]);
                aggL[tid] = m;
            } else {
                float s = 0.f;
#pragma unroll
                for (int vsi = 0; vsi < NSPLIT; ++vsi)
                    s += pb[vsi * stride];
                aggL[tid] = s * (1.0f / (float)NV);
            }
        }
        __syncthreads();

        if (tid < NOUT) {
            int n = tid;
            const float* wr = W_out + (size_t)(NFT + a * NC2) * NOUT + n;
            float acc = W_out[(size_t)(NFT + NA * NC2 + a) * NOUT + n];
#pragma unroll 8
            for (int c = 0; c < NC2; ++c)
                acc = fmaf(aggL[c], wr[(size_t)c * NOUT], acc);
            Gp[(size_t)(b * NA + a) * NOUT + n] = acc;
        }
        __syncthreads();   // readers done before next rep rewrites aggL
    }
}

// ---------------------------------------------------------------------------
// K4 (MFMA): DIAGNOSTIC x3 repeat (idempotent reps, barrier-separated).
// ---------------------------------------------------------------------------
#define MB 64

__device__ inline void f2hl(float v, ushort& h, ushort& l) {
    __hip_bfloat16 hb = __float2bfloat16(v);
    float hf = __bfloat162float(hb);
    __hip_bfloat16 lb = __float2bfloat16(v - hf);
    h = *(ushort*)&hb;
    l = *(ushort*)&lb;
}

__global__ void k4_mfma(const float* __restrict__ x,
                        const float* __restrict__ ewbuf,
                        const float* __restrict__ Gp,
                        const float* __restrict__ W_out,
                        const float* __restrict__ b_out,
                        float* __restrict__ out) {
    __shared__ ushort BsH[1024 * 8];   // 16 KB
    __shared__ ushort BsL[1024 * 8];   // 16 KB
    __shared__ float  bs[NOUT];

    int rb = blockIdx.x;
    int b  = blockIdx.y;
    int tid = threadIdx.x;
    int rowbase = b * NV + rb * MB;

#pragma unroll 1
    for (int rep = 0; rep < 3; ++rep) {
        // ---- stage B in fragment-order ----
#pragma unroll
        for (int it = 0; it < 4; ++it) {
            int u = it * 256 + tid;
            int n = u & 127, koct = u >> 7;
            float v[8];
            if (koct < 2) {
#pragma unroll
                for (int j = 0; j < 8; ++j)
                    v[j] = W_out[(size_t)(koct * 8 + j) * NOUT + n];
            } else if (koct < 6) {
#pragma unroll
                for (int j = 0; j < 8; ++j)
                    v[j] = Gp[(size_t)b * NA * NOUT + (size_t)(koct * 8 + j - 16) * NOUT + n];
            } else {
#pragma unroll
                for (int j = 0; j < 8; ++j) v[j] = 0.f;
            }
            ushort h[8], l[8];
#pragma unroll
            for (int j = 0; j < 8; ++j) f2hl(v[j], h[j], l[j]);
            int cidx = ((koct >> 2) * 512) + ((n >> 4) * 64) + ((koct & 3) * 16) + (n & 15);
            *(bf16x8*)&BsH[cidx * 8] = *(bf16x8*)h;
            *(bf16x8*)&BsL[cidx * 8] = *(bf16x8*)l;
        }
        if (tid < NOUT) bs[tid] = b_out[tid];

        // ---- A fragments direct from global ----
        int w = tid >> 6, lane = tid & 63;
        int r16 = lane & 15, kg = lane >> 4;
        int arow = w * 16 + r16;
        int grow = rowbase + arow;

        float a0[8], a1[8];
        if (kg < 2) {
            *(float4*)&a0[0] = *(const float4*)&x[(size_t)grow * NFT + kg * 8];
            *(float4*)&a0[4] = *(const float4*)&x[(size_t)grow * NFT + kg * 8 + 4];
            *(float4*)&a1[0] = *(const float4*)&ewbuf[(size_t)grow * NA + 16 + kg * 8];
            *(float4*)&a1[4] = *(const float4*)&ewbuf[(size_t)grow * NA + 16 + kg * 8 + 4];
        } else {
            *(float4*)&a0[0] = *(const float4*)&ewbuf[(size_t)grow * NA + (kg - 2) * 8];
            *(float4*)&a0[4] = *(const float4*)&ewbuf[(size_t)grow * NA + (kg - 2) * 8 + 4];
#pragma unroll
            for (int j = 0; j < 8; ++j) a1[j] = 0.f;
        }
        ushort ah0[8], al0[8], ah1[8], al1[8];
#pragma unroll
        for (int j = 0; j < 8; ++j) f2hl(a0[j], ah0[j], al0[j]);
#pragma unroll
        for (int j = 0; j < 8; ++j) f2hl(a1[j], ah1[j], al1[j]);
        bf16x8 AH0 = *(bf16x8*)ah0, AL0 = *(bf16x8*)al0;
        bf16x8 AH1 = *(bf16x8*)ah1, AL1 = *(bf16x8*)al1;

        __syncthreads();

        int orow0 = rowbase + w * 16 + kg * 4;

#pragma unroll
        for (int nt = 0; nt < 8; ++nt) {
            int n = nt * 16 + r16;
            bf16x8 BH0 = *(const bf16x8*)&BsH[(nt * 64 + lane) * 8];
            bf16x8 BH1 = *(const bf16x8*)&BsH[(512 + nt * 64 + lane) * 8];
            bf16x8 BL0 = *(const bf16x8*)&BsL[(nt * 64 + lane) * 8];
            bf16x8 BL1 = *(const bf16x8*)&BsL[(512 + nt * 64 + lane) * 8];
            float bias = bs[n];
            f32x4 acc = {bias, bias, bias, bias};
            acc = __builtin_amdgcn_mfma_f32_16x16x32_bf16(AH0, BH0, acc, 0, 0, 0);
            acc = __builtin_amdgcn_mfma_f32_16x16x32_bf16(AL0, BH0, acc, 0, 0, 0);
            acc = __builtin_amdgcn_mfma_f32_16x16x32_bf16(AH0, BL0, acc, 0, 0, 0);
            acc = __builtin_amdgcn_mfma_f32_16x16x32_bf16(AH1, BH1, acc, 0, 0, 0);
            acc = __builtin_amdgcn_mfma_f32_16x16x32_bf16(AL1, BH1, acc, 0, 0, 0);
            acc = __builtin_amdgcn_mfma_f32_16x16x32_bf16(AH1, BL1, acc, 0, 0, 0);
#pragma unroll
            for (int rg = 0; rg < 4; ++rg) {
                float s = acc[rg];
                s = fminf(fmaxf(s, -15.f), 15.f);
                float e = __expf(2.f * s);
                out[(size_t)(orow0 + rg) * NOUT + n] =
                    (e - 1.f) * __builtin_amdgcn_rcpf(e + 1.f);
            }
        }
        __syncthreads();   // readers done before next rep restages Bs
    }
}

// ---------------------------------------------------------------------------
extern "C" void kernel_launch(void* const* d_in, const int* in_sizes, int n_in,
                              void* d_out, int out_size, void* d_ws, size_t ws_size,
                              hipStream_t stream) {
    const float* x     = (const float*)d_in[0];
    const float* W_flr = (const float*)d_in[1];
    const float* b_flr = (const float*)d_in[2];
    const float* W_s   = (const float*)d_in[3];
    const float* b_s   = (const float*)d_in[4];
    const float* W_out = (const float*)d_in[5];
    const float* b_out = (const float*)d_in[6];
    float* out = (float*)d_out;

    // workspace layout (floats)
    float* ewbuf = (float*)d_ws;                              // B*V*32     = 1,048,576
    float* part  = ewbuf + (size_t)NB * NV * NA;              // 512*32*192 = 3,145,728
    float* Gp    = part  + (size_t)NB * NSPLIT * NA * NC2;    // B*A*128    =   131,072

    // K2p: grid (B, 16) x 512
    {
        dim3 g(NB, NSPLIT);
        k2p<<<g, 512, 0, stream>>>(x, W_flr, b_flr, W_s, b_s, ewbuf, part);
    }
    // K23 (x3 diagnostic): grid (B, A) x 192
    {
        dim3 g(NB, NA);
        k23<<<g, 192, 0, stream>>>(part, W_out, Gp);
    }
    // K4 (x3 diagnostic): grid (16 row-blocks, B) x 256
    {
        dim3 g(NV / MB, NB);
        k4_mfma<<<g, 256, 0, stream>>>(x, ewbuf, Gp, W_out, b_out, out);
    }
}

// Round 17
// 38.661 us; speedup vs baseline: 1.7281x; 1.7281x over previous
//
#include <hip/hip_runtime.h>
#include <hip/hip_bf16.h>
#include <math.h>

#define NB 32      // B
#define NV 1024    // V
#define NFT 16     // F
#define NA 32      // A
#define NP 64      // P
#define NOUT 128   // NF
#define NC 96      // C = P + A
#define NC2 192    // 2C

#define NSPLIT 16            // V splits
#define VPB 64               // rows per k2p block

typedef __attribute__((ext_vector_type(8))) short bf16x8;
typedef __attribute__((ext_vector_type(4))) float f32x4;

__device__ inline void f2hl(float v, ushort& h, ushort& l) {
    __hip_bfloat16 hb = __float2bfloat16(v);
    float hf = __bfloat162float(hb);
    __hip_bfloat16 lb = __float2bfloat16(v - hf);
    h = *(ushort*)&hb;
    l = *(ushort*)&lb;
}

// ---------------------------------------------------------------------------
// K2p: fused vertex transform + partial (max,sum) aggregation (R9 body,
// measured 9.6 us) + NEW: emits x and ew as bf16 hi/lo for k4.
// ---------------------------------------------------------------------------
__global__ __launch_bounds__(512, 2)
void k2p(const float* __restrict__ x,
         const float* __restrict__ W_flr,
         const float* __restrict__ b_flr,
         const float* __restrict__ W_s,
         const float* __restrict__ b_s,
         float* __restrict__ part,
         ushort* __restrict__ xbfH, ushort* __restrict__ xbfL,
         ushort* __restrict__ ewH,  ushort* __restrict__ ewL) {
    __shared__ float xs[VPB][NFT];        // 4 KB
    __shared__ float fs[VPB][NC];         // 24 KB

    int b = blockIdx.x, vs = blockIdx.y, tid = threadIdx.x;
    int rowbase = b * NV + vs * VPB;

    // stage x (256 float4) + convert to bf16 hi/lo
    if (tid < 256) {
        float4 v = ((const float4*)(x + (size_t)rowbase * NFT))[tid];
        ((float4*)xs)[tid] = v;
        int r = tid >> 2, ko = (tid & 3) * 4;
        float vv[4] = {v.x, v.y, v.z, v.w};
        ushort h[4], l[4];
#pragma unroll
        for (int j = 0; j < 4; ++j) f2hl(vv[j], h[j], l[j]);
        uint2 hp = { (uint)h[0] | ((uint)h[1] << 16), (uint)h[2] | ((uint)h[3] << 16) };
        uint2 lp = { (uint)l[0] | ((uint)l[1] << 16), (uint)l[2] | ((uint)l[3] << 16) };
        *(uint2*)&xbfH[(size_t)(rowbase + r) * NFT + ko] = hp;
        *(uint2*)&xbfL[(size_t)(rowbase + r) * NFT + ko] = lp;
    }
    __syncthreads();

    // phase A: c = tid&127 (<96 active), rh = tid>>7 -> rows rh*16..+15
    {
        int c  = tid & 127;
        int rh = tid >> 7;
        if (c < NC) {
            float Wcol[NFT], bias;
            if (c < NP) {
                bias = b_flr[c];
#pragma unroll
                for (int k = 0; k < NFT; ++k) Wcol[k] = W_flr[k * NP + c];
            } else {
                int a = c - NP;
                bias = b_s[a];
#pragma unroll
                for (int k = 0; k < NFT; ++k) Wcol[k] = W_s[k * NA + a];
            }
#pragma unroll
            for (int r0 = 0; r0 < 16; ++r0) {
                int r = rh * 16 + r0;
                float xr[NFT];
#pragma unroll
                for (int q = 0; q < 4; ++q)
                    ((float4*)xr)[q] = ((const float4*)xs[r])[q];
                float acc = bias;
#pragma unroll
                for (int k = 0; k < NFT; ++k)
                    acc = fmaf(xr[k], Wcol[k], acc);
                if (c >= NP) {
                    acc = __expf(-acc * acc);
                    ushort h, l;
                    f2hl(acc, h, l);
                    ewH[(size_t)(rowbase + r) * NA + (c - NP)] = h;
                    ewL[(size_t)(rowbase + r) * NA + (c - NP)] = l;
                }
                fs[r][c] = acc;
            }
        }
    }
    __syncthreads();

    // phase B: thread owns 1a x 6c over all 64 rows
    int a  = tid >> 4;
    int c0 = (tid & 15) * 6;
    int ea = NP + a;

    float sm[6], mx[6];
#pragma unroll
    for (int j = 0; j < 6; ++j) { sm[j] = 0.f; mx[j] = -INFINITY; }

#pragma unroll 4
    for (int r = 0; r < VPB; ++r) {
        float e = fs[r][ea];
        float2 fA = *(const float2*)&fs[r][c0];
        float2 fB = *(const float2*)&fs[r][c0 + 2];
        float2 fC = *(const float2*)&fs[r][c0 + 4];
        float ff[6] = {fA.x, fA.y, fB.x, fB.y, fC.x, fC.y};
#pragma unroll
        for (int j = 0; j < 6; ++j) {
            float p = e * ff[j];
            sm[j] += p;
            mx[j] = fmaxf(mx[j], p);
        }
    }

    float* pb = part + (size_t)((b * NSPLIT + vs) * NA + a) * NC2;
#pragma unroll
    for (int q = 0; q < 3; ++q) {
        float2 vm = {mx[2 * q], mx[2 * q + 1]};
        float2 vsum = {sm[2 * q], sm[2 * q + 1]};
        *(float2*)&pb[c0 + 2 * q]      = vm;
        *(float2*)&pb[NC + c0 + 2 * q] = vsum;
    }
}

// ---------------------------------------------------------------------------
// K23: combine partials -> agg -> G matmul; NEW: writes result directly as
// bf16 hi/lo fragment-order Bbuf for k4 (one conversion per value, not 16).
// a==0 block also emits W_head (koct 0-1), bias row (k=48, koct 6 j=0), and
// zero tails. chunk(n,koct) index: ((koct>>2)*512)+((n>>4)*64)+((koct&3)*16)+(n&15)
// ---------------------------------------------------------------------------
__global__ void k23(const float* __restrict__ part,
                    const float* __restrict__ W_out,
                    const float* __restrict__ b_out,
                    ushort* __restrict__ BbH, ushort* __restrict__ BbL) {
    __shared__ float aggL[NC2];
    int b = blockIdx.x, a = blockIdx.y, tid = threadIdx.x;

    {
        const float* pb = part + (size_t)(b * NSPLIT * NA + a) * NC2 + tid;
        const size_t stride = (size_t)NA * NC2;
        if (tid < NC) {
            float m = -INFINITY;
#pragma unroll
            for (int vsi = 0; vsi < NSPLIT; ++vsi)
                m = fmaxf(m, pb[vsi * stride]);
            aggL[tid] = m;
        } else {
            float s = 0.f;
#pragma unroll
            for (int vsi = 0; vsi < NSPLIT; ++vsi)
                s += pb[vsi * stride];
            aggL[tid] = s * (1.0f / (float)NV);
        }
    }
    __syncthreads();

    if (tid < NOUT) {
        int n = tid;
        ushort* bh = BbH + (size_t)b * 8192;
        ushort* bl = BbL + (size_t)b * 8192;

        const float* wr = W_out + (size_t)(NFT + a * NC2) * NOUT + n;
        float acc = W_out[(size_t)(NFT + NA * NC2 + a) * NOUT + n];
#pragma unroll 8
        for (int c = 0; c < NC2; ++c)
            acc = fmaf(aggL[c], wr[(size_t)c * NOUT], acc);

        // write Gp value into fragment-order Bbuf: k = 16+a
        {
            ushort h, l;
            f2hl(acc, h, l);
            int koct = 2 + (a >> 3), j = a & 7;
            int ci = ((koct >> 2) * 512) + ((n >> 4) * 64) + ((koct & 3) * 16) + (n & 15);
            bh[ci * 8 + j] = h;
            bl[ci * 8 + j] = l;
        }

        if (a == 0) {
            // W_head: k = 0..15 (koct 0,1)
#pragma unroll
            for (int k = 0; k < NFT; ++k) {
                ushort h, l;
                f2hl(W_out[(size_t)k * NOUT + n], h, l);
                int ci = ((n >> 4) * 64) + ((k >> 3) * 16) + (n & 15);
                bh[ci * 8 + (k & 7)] = h;
                bl[ci * 8 + (k & 7)] = l;
            }
            // koct 6: j=0 -> bias (k=48), j=1..7 -> 0 ; koct 7: all 0
            {
                ushort h, l;
                f2hl(b_out[n], h, l);
                int ci6 = 512 + ((n >> 4) * 64) + (2 * 16) + (n & 15);
                int ci7 = 512 + ((n >> 4) * 64) + (3 * 16) + (n & 15);
                bh[ci6 * 8 + 0] = h;
                bl[ci6 * 8 + 0] = l;
#pragma unroll
                for (int j = 1; j < 8; ++j) { bh[ci6 * 8 + j] = 0; bl[ci6 * 8 + j] = 0; }
#pragma unroll
                for (int j = 0; j < 8; ++j) { bh[ci7 * 8 + j] = 0; bl[ci7 * 8 + j] = 0; }
            }
        }
    }
}

// ---------------------------------------------------------------------------
// K4 (MFMA, pure-consume): no LDS, no barriers, no conversions.
// A: four ushort8 loads from xbf/ew (L2). B: lane-linear contiguous 1KB
// wave-loads from Bbuf (L2). Bias arrives via A[k=48]=1.0 x B[48][n].
// Block = 32 rows x 128 n (4 waves: rgrp = w&1, nhalf = w>>1), grid (32,32)
// -> 1024 blocks = 4 blocks/CU = 16 waves/CU.
// ---------------------------------------------------------------------------
#define MB4 32

__global__ __launch_bounds__(256, 4)
void k4_mfma(const ushort* __restrict__ xbfH, const ushort* __restrict__ xbfL,
             const ushort* __restrict__ ewH,  const ushort* __restrict__ ewL,
             const ushort* __restrict__ BbH,  const ushort* __restrict__ BbL,
             float* __restrict__ out) {
    int rb = blockIdx.x, b = blockIdx.y;
    int tid = threadIdx.x;
    int w = tid >> 6, lane = tid & 63;
    int r16 = lane & 15, kg = lane >> 4;
    int rgrp = w & 1, nh = w >> 1;
    int rowbase = b * NV + rb * MB4;
    int grow = rowbase + rgrp * 16 + r16;

    bf16x8 AH0, AH1, AL0, AL1;
    if (kg < 2) {
        AH0 = *(const bf16x8*)&xbfH[(size_t)grow * NFT + kg * 8];
        AL0 = *(const bf16x8*)&xbfL[(size_t)grow * NFT + kg * 8];
        AH1 = *(const bf16x8*)&ewH[(size_t)grow * NA + 16 + kg * 8];
        AL1 = *(const bf16x8*)&ewL[(size_t)grow * NA + 16 + kg * 8];
    } else {
        AH0 = *(const bf16x8*)&ewH[(size_t)grow * NA + (kg - 2) * 8];
        AL0 = *(const bf16x8*)&ewL[(size_t)grow * NA + (kg - 2) * 8];
        ushort one[8] = {0, 0, 0, 0, 0, 0, 0, 0};
        if (kg == 2) one[0] = 0x3F80;          // bf16 1.0 at k=48 (bias row)
        AH1 = *(bf16x8*)one;
        AL1 = (bf16x8){0, 0, 0, 0, 0, 0, 0, 0};
    }

    const ushort* bh = BbH + (size_t)b * 8192;
    const ushort* bl = BbL + (size_t)b * 8192;
    int orow0 = rowbase + rgrp * 16 + kg * 4;

#pragma unroll 2
    for (int t = 0; t < 4; ++t) {
        int nt = nh * 4 + t;
        int n = nt * 16 + r16;
        bf16x8 BH0 = *(const bf16x8*)&bh[(size_t)(nt * 64 + lane) * 8];
        bf16x8 BH1 = *(const bf16x8*)&bh[(size_t)(512 + nt * 64 + lane) * 8];
        bf16x8 BL0 = *(const bf16x8*)&bl[(size_t)(nt * 64 + lane) * 8];
        bf16x8 BL1 = *(const bf16x8*)&bl[(size_t)(512 + nt * 64 + lane) * 8];
        f32x4 acc = {0.f, 0.f, 0.f, 0.f};
        acc = __builtin_amdgcn_mfma_f32_16x16x32_bf16(AH0, BH0, acc, 0, 0, 0);
        acc = __builtin_amdgcn_mfma_f32_16x16x32_bf16(AL0, BH0, acc, 0, 0, 0);
        acc = __builtin_amdgcn_mfma_f32_16x16x32_bf16(AH0, BL0, acc, 0, 0, 0);
        acc = __builtin_amdgcn_mfma_f32_16x16x32_bf16(AH1, BH1, acc, 0, 0, 0);
        acc = __builtin_amdgcn_mfma_f32_16x16x32_bf16(AL1, BH1, acc, 0, 0, 0);
        acc = __builtin_amdgcn_mfma_f32_16x16x32_bf16(AH1, BL1, acc, 0, 0, 0);
#pragma unroll
        for (int rg = 0; rg < 4; ++rg) {
            float s = acc[rg];
            s = fminf(fmaxf(s, -15.f), 15.f);
            float e = __expf(2.f * s);
            out[(size_t)(orow0 + rg) * NOUT + n] =
                (e - 1.f) * __builtin_amdgcn_rcpf(e + 1.f);
        }
    }
}

// ---------------------------------------------------------------------------
extern "C" void kernel_launch(void* const* d_in, const int* in_sizes, int n_in,
                              void* d_out, int out_size, void* d_ws, size_t ws_size,
                              hipStream_t stream) {
    const float* x     = (const float*)d_in[0];
    const float* W_flr = (const float*)d_in[1];
    const float* b_flr = (const float*)d_in[2];
    const float* W_s   = (const float*)d_in[3];
    const float* b_s   = (const float*)d_in[4];
    const float* W_out = (const float*)d_in[5];
    const float* b_out = (const float*)d_in[6];
    float* out = (float*)d_out;

    // workspace layout
    float*  part = (float*)d_ws;                       // 3,145,728 floats (12.6 MB)
    ushort* xbfH = (ushort*)(part + 3145728);          //   524,288 ushorts
    ushort* xbfL = xbfH + 524288;
    ushort* ewH  = xbfL + 524288;                      // 1,048,576
    ushort* ewL  = ewH + 1048576;
    ushort* BbH  = ewL + 1048576;                      //   262,144
    ushort* BbL  = BbH + 262144;

    // K2p: grid (B, 16) x 512
    {
        dim3 g(NB, NSPLIT);
        k2p<<<g, 512, 0, stream>>>(x, W_flr, b_flr, W_s, b_s,
                                   part, xbfH, xbfL, ewH, ewL);
    }
    // K23: grid (B, A) x 192
    {
        dim3 g(NB, NA);
        k23<<<g, 192, 0, stream>>>(part, W_out, b_out, BbH, BbL);
    }
    // K4: grid (32 row-blocks, B) x 256
    {
        dim3 g(NV / MB4, NB);
        k4_mfma<<<g, 256, 0, stream>>>(xbfH, xbfL, ewH, ewL, BbH, BbL, out);
    }
}